// Round 1
// baseline (430.492 us; speedup 1.0000x reference)
//
#include <hip/hip_runtime.h>
#include <hip/hip_bf16.h>

#define NR   4096
#define DIM  1024
#define NE   8

#define BM 128
#define BN 128
#define BK 32

typedef __attribute__((ext_vector_type(8))) short  bf16x8;
typedef __attribute__((ext_vector_type(8))) ushort u16x8;
typedef __attribute__((ext_vector_type(4))) float  f32x4;

__device__ __forceinline__ ushort f2bf(float f) {
    union { __hip_bfloat16 h; ushort u; } cv;
    cv.h = __float2bfloat16(f);   // RNE
    return cv.u;
}

// ---------------- gating: H = x@Wg + noise*softplus(x@Wn), top-2, softmax ----
// one wave per row; appends (row, weight) to per-(pass,expert) buckets.
__global__ __launch_bounds__(256)
void gate_kernel(const float* __restrict__ x, const float* __restrict__ noise,
                 const float* __restrict__ Wg, const float* __restrict__ Wn,
                 int* __restrict__ cnt, int* __restrict__ idxl, float* __restrict__ wl) {
    const int wid  = threadIdx.x >> 6;
    const int lane = threadIdx.x & 63;
    const int row  = blockIdx.x * 4 + wid;
    const float* xr = x + (size_t)row * DIM;

    float ag[NE], an[NE];
#pragma unroll
    for (int e = 0; e < NE; ++e) { ag[e] = 0.f; an[e] = 0.f; }

    for (int k = lane; k < DIM; k += 64) {
        float xv = xr[k];
        const float4* g4 = (const float4*)(Wg + (size_t)k * NE);
        const float4* n4 = (const float4*)(Wn + (size_t)k * NE);
        float4 g0 = g4[0], g1 = g4[1];
        float4 n0 = n4[0], n1 = n4[1];
        ag[0] += xv * g0.x; ag[1] += xv * g0.y; ag[2] += xv * g0.z; ag[3] += xv * g0.w;
        ag[4] += xv * g1.x; ag[5] += xv * g1.y; ag[6] += xv * g1.z; ag[7] += xv * g1.w;
        an[0] += xv * n0.x; an[1] += xv * n0.y; an[2] += xv * n0.z; an[3] += xv * n0.w;
        an[4] += xv * n1.x; an[5] += xv * n1.y; an[6] += xv * n1.z; an[7] += xv * n1.w;
    }
#pragma unroll
    for (int e = 0; e < NE; ++e) {
#pragma unroll
        for (int off = 32; off > 0; off >>= 1) {
            ag[e] += __shfl_down(ag[e], off, 64);
            an[e] += __shfl_down(an[e], off, 64);
        }
    }
    if (lane == 0) {
        float H[NE];
#pragma unroll
        for (int e = 0; e < NE; ++e) {
            float z  = an[e];
            float sp = (z > 0.f) ? (z + log1pf(expf(-z))) : log1pf(expf(z));
            H[e] = ag[e] + noise[e] * sp;
        }
        int e0 = 0; float v0 = H[0];
#pragma unroll
        for (int e = 1; e < NE; ++e) if (H[e] > v0) { v0 = H[e]; e0 = e; }
        int e1 = -1; float v1 = 0.f;
#pragma unroll
        for (int e = 0; e < NE; ++e)
            if (e != e0 && (e1 < 0 || H[e] > v1)) { v1 = H[e]; e1 = e; }
        float r  = expf(v1 - v0);           // v1 <= v0, r in (0,1]
        float w0 = 1.f / (1.f + r);
        float w1 = 1.f - w0;

        int p0 = atomicAdd(&cnt[e0], 1);
        idxl[(size_t)e0 * NR + p0] = row;
        wl [(size_t)e0 * NR + p0] = w0;
        int p1 = atomicAdd(&cnt[NE + e1], 1);
        idxl[(size_t)(NE + e1) * NR + p1] = row;
        wl [(size_t)(NE + e1) * NR + p1] = w1;
    }
}

__global__ void zero_cnt(int* cnt) { if (threadIdx.x < 2 * NE) cnt[threadIdx.x] = 0; }

// ---------------- grouped expert GEMM: out[rows] (=|+=) w * (X@We[e] + be[e]) ---
// PASS 0: top-1 buckets, plain store. PASS 1: top-2 buckets, read-modify-write.
template<int PASS>
__global__ __launch_bounds__(256)
void expert_gemm(const float* __restrict__ x, const float* __restrict__ We,
                 const float* __restrict__ be, const int* __restrict__ cnt,
                 const int* __restrict__ idxl, const float* __restrict__ wl,
                 float* __restrict__ out) {
    const int e      = blockIdx.z;
    const int bucket = PASS * NE + e;
    const int count  = cnt[bucket];
    const int t      = blockIdx.x;
    if (t * BM >= count) return;
    const int c0 = blockIdx.y * BN;

    const int*   rows = idxl + (size_t)bucket * NR + t * BM;
    const float* wrow = wl   + (size_t)bucket * NR + t * BM;
    const int nrows   = min(BM, count - t * BM);

    __shared__ __align__(16) ushort Al[BM][BK + 8];   // [row][k], +8 pad
    __shared__ __align__(16) ushort Bl[BN][BK + 8];   // [col][k] (We^T), +8 pad

    const int tid  = threadIdx.x;
    const int wid  = tid >> 6, lane = tid & 63;
    const int wr   = (wid >> 1) * 64, wc = (wid & 1) * 64;
    const int l16  = lane & 15, lhi = lane >> 4;

    f32x4 acc[4][4];
#pragma unroll
    for (int i = 0; i < 4; ++i)
#pragma unroll
        for (int j = 0; j < 4; ++j) { f32x4 z = {0.f, 0.f, 0.f, 0.f}; acc[i][j] = z; }

    // A staging: 2 threads per LDS row (k 0..15 | 16..31)
    const int arow  = tid >> 1;
    const int apart = (tid & 1) * 16;
    const float* asrc = (arow < nrows) ? (x + (size_t)rows[arow] * DIM + apart) : nullptr;

    const float* Bb = We + (size_t)e * DIM * DIM + c0;   // We[e][k][c0+..]

    for (int k0 = 0; k0 < DIM; k0 += BK) {
        __syncthreads();
        // ---- stage A (gathered rows, f32 -> bf16) ----
        {
            ushort tmp[16];
            if (asrc) {
                const float4* s = (const float4*)(asrc + k0);
#pragma unroll
                for (int q = 0; q < 4; ++q) {
                    float4 v = s[q];
                    tmp[q * 4 + 0] = f2bf(v.x); tmp[q * 4 + 1] = f2bf(v.y);
                    tmp[q * 4 + 2] = f2bf(v.z); tmp[q * 4 + 3] = f2bf(v.w);
                }
            } else {
#pragma unroll
                for (int q = 0; q < 16; ++q) tmp[q] = 0;
            }
            *(u16x8*)&Al[arow][apart]     = *(u16x8*)&tmp[0];
            *(u16x8*)&Al[arow][apart + 8] = *(u16x8*)&tmp[8];
        }
        // ---- stage B transposed: Bl[col][k] <- We[e][k][c] ----
#pragma unroll
        for (int j = 0; j < 2; ++j) {
            int uid = j * 256 + tid;          // 512 units: (col, k-group-of-8)
            int c   = uid & 127, kg = uid >> 7;
            const float* bs = Bb + (size_t)(k0 + kg * 8) * DIM + c;
            ushort tmp[8];
#pragma unroll
            for (int q = 0; q < 8; ++q) tmp[q] = f2bf(bs[(size_t)q * DIM]);
            *(u16x8*)&Bl[c][kg * 8] = *(u16x8*)&tmp[0];
        }
        __syncthreads();
        // ---- fragments + MFMA ----
        bf16x8 af[4], bfr[4];
#pragma unroll
        for (int m = 0; m < 4; ++m) af[m]  = *(bf16x8*)&Al[wr + m * 16 + l16][lhi * 8];
#pragma unroll
        for (int n = 0; n < 4; ++n) bfr[n] = *(bf16x8*)&Bl[wc + n * 16 + l16][lhi * 8];
#pragma unroll
        for (int m = 0; m < 4; ++m)
#pragma unroll
            for (int n = 0; n < 4; ++n)
                acc[m][n] = __builtin_amdgcn_mfma_f32_16x16x32_bf16(af[m], bfr[n], acc[m][n], 0, 0, 0);
    }

    // ---- epilogue: val = w * (acc + be);  D layout: col=lane&15, row=(lane>>4)*4+reg ----
    float bev[4];
#pragma unroll
    for (int n = 0; n < 4; ++n) bev[n] = be[(size_t)e * DIM + c0 + wc + n * 16 + l16];
#pragma unroll
    for (int m = 0; m < 4; ++m) {
#pragma unroll
        for (int r = 0; r < 4; ++r) {
            int rl = wr + m * 16 + lhi * 4 + r;
            if (rl < nrows) {
                int   grow = rows[rl];
                float w    = wrow[rl];
                float* op  = out + (size_t)grow * DIM + c0 + wc;
#pragma unroll
                for (int n = 0; n < 4; ++n) {
                    float val = w * (acc[m][n][r] + bev[n]);
                    int   col = n * 16 + l16;
                    if (PASS == 0) op[col] = val;
                    else           op[col] += val;
                }
            }
        }
    }
}

extern "C" void kernel_launch(void* const* d_in, const int* in_sizes, int n_in,
                              void* d_out, int out_size, void* d_ws, size_t ws_size,
                              hipStream_t stream) {
    const float* x     = (const float*)d_in[0];
    const float* noise = (const float*)d_in[1];
    const float* Wg    = (const float*)d_in[2];
    const float* Wn    = (const float*)d_in[3];
    const float* We    = (const float*)d_in[4];
    const float* be    = (const float*)d_in[5];
    float* out = (float*)d_out;

    char* ws   = (char*)d_ws;
    int*   cnt  = (int*)ws;                                        // 16 ints
    int*   idxl = (int*)(ws + 256);                                // 2*8*NR ints
    float* wl   = (float*)(ws + 256 + (size_t)2 * NE * NR * 4);    // 2*8*NR floats

    zero_cnt<<<1, 64, 0, stream>>>(cnt);
    gate_kernel<<<NR / 4, 256, 0, stream>>>(x, noise, Wg, Wn, cnt, idxl, wl);

    dim3 grid(NR / BM, DIM / BN, NE);
    expert_gemm<0><<<grid, 256, 0, stream>>>(x, We, be, cnt, idxl, wl, out);
    expert_gemm<1><<<grid, 256, 0, stream>>>(x, We, be, cnt, idxl, wl, out);
}

// Round 2
// 151.898 us; speedup vs baseline: 2.8341x; 2.8341x over previous
//
#include <hip/hip_runtime.h>
#include <hip/hip_bf16.h>
#include <stdint.h>

#define NR   4096
#define DIM  1024
#define NE   8
#define BM   128
#define BN   128
#define GBK  64

typedef __attribute__((ext_vector_type(8))) short  bf16x8;
typedef __attribute__((ext_vector_type(8))) ushort u16x8;
typedef __attribute__((ext_vector_type(4))) float  f32x4;

__device__ __forceinline__ ushort f2bf(float f) {
    union { __hip_bfloat16 h; ushort u; } cv;
    cv.h = __float2bfloat16(f);   // RNE
    return cv.u;
}

// async global->LDS, 16B per lane; LDS dest = wave-uniform base + lane*16 (HW)
__device__ __forceinline__ void gload16(const void* g, void* l) {
    __builtin_amdgcn_global_load_lds(
        (const __attribute__((address_space(1))) unsigned int*)g,
        (__attribute__((address_space(3))) unsigned int*)l, 16, 0, 0);
}

// ---------------- convert x (f32 -> bf16), also zero the bucket counters ----
__global__ __launch_bounds__(256)
void convert_x(const float* __restrict__ x, ushort* __restrict__ xbf, int* __restrict__ cnt) {
    if (blockIdx.x == 0 && threadIdx.x < 2 * NE) cnt[threadIdx.x] = 0;
    const int n4 = NR * DIM / 4;
    for (int i = blockIdx.x * blockDim.x + threadIdx.x; i < n4; i += gridDim.x * blockDim.x) {
        float4 v = ((const float4*)x)[i];
        ushort4 o;
        o.x = f2bf(v.x); o.y = f2bf(v.y); o.z = f2bf(v.z); o.w = f2bf(v.w);
        ((ushort4*)xbf)[i] = o;
    }
}

// ---------------- convert+transpose We: [e][k][c] f32 -> WeT [e][c][k] bf16 ---
__global__ __launch_bounds__(256)
void conv_we(const float* __restrict__ We, ushort* __restrict__ WeT) {
    const int b  = blockIdx.x;              // e*256 + kt*16 + ct
    const int e  = b >> 8, kt = (b >> 4) & 15, ct = b & 15;
    __shared__ float T[64][68];             // 64x64 tile, padded
    const float* src = We + ((size_t)e * DIM + (size_t)kt * 64) * DIM + ct * 64;
#pragma unroll
    for (int j = 0; j < 4; ++j) {
        int idx = threadIdx.x + j * 256;    // 1024 float4 units (64 rows x 16)
        int r = idx >> 4, c4 = idx & 15;
        float4 v = *(const float4*)(src + (size_t)r * DIM + c4 * 4);
        *(float4*)&T[r][c4 * 4] = v;
    }
    __syncthreads();
    ushort* dst = WeT + ((size_t)e * DIM + (size_t)ct * 64) * DIM + kt * 64;
#pragma unroll
    for (int j = 0; j < 2; ++j) {
        int u = threadIdx.x + j * 256;      // 512 units: c=u/8, chunk=u%8 (8 bf16)
        int c = u >> 3, ch = u & 7;
        ushort tmp[8];
#pragma unroll
        for (int q = 0; q < 8; ++q) tmp[q] = f2bf(T[ch * 8 + q][c]);
        *(u16x8*)(dst + (size_t)c * DIM + ch * 8) = *(u16x8*)tmp;
    }
}

// ---------------- gating: 16 lanes per row, width-16 shuffle reduce ----------
__global__ __launch_bounds__(256)
void gate_v2(const float* __restrict__ x, const float* __restrict__ noise,
             const float* __restrict__ Wg, const float* __restrict__ Wn,
             int* __restrict__ cnt, int* __restrict__ idxl, float* __restrict__ wl) {
    const int tid = threadIdx.x;
    const int rl  = tid >> 4, l16 = tid & 15;
    const int row = blockIdx.x * 16 + rl;
    const float* xr = x + (size_t)row * DIM;

    float ag[NE], an[NE];
#pragma unroll
    for (int e = 0; e < NE; ++e) { ag[e] = 0.f; an[e] = 0.f; }

    for (int j = 0; j < 16; ++j) {
        const int k = j * 64 + l16 * 4;
        const float4 xv = *(const float4*)(xr + k);
        const float4* g = (const float4*)(Wg + (size_t)k * NE);
        const float4* w = (const float4*)(Wn + (size_t)k * NE);
#pragma unroll
        for (int q = 0; q < 4; ++q) {
            const float xq = (q == 0) ? xv.x : (q == 1) ? xv.y : (q == 2) ? xv.z : xv.w;
            float4 g0 = g[q * 2], g1 = g[q * 2 + 1];
            float4 n0 = w[q * 2], n1 = w[q * 2 + 1];
            ag[0] += xq * g0.x; ag[1] += xq * g0.y; ag[2] += xq * g0.z; ag[3] += xq * g0.w;
            ag[4] += xq * g1.x; ag[5] += xq * g1.y; ag[6] += xq * g1.z; ag[7] += xq * g1.w;
            an[0] += xq * n0.x; an[1] += xq * n0.y; an[2] += xq * n0.z; an[3] += xq * n0.w;
            an[4] += xq * n1.x; an[5] += xq * n1.y; an[6] += xq * n1.z; an[7] += xq * n1.w;
        }
    }
#pragma unroll
    for (int e = 0; e < NE; ++e) {
#pragma unroll
        for (int off = 8; off; off >>= 1) {
            ag[e] += __shfl_down(ag[e], off, 16);
            an[e] += __shfl_down(an[e], off, 16);
        }
    }
    if (l16 == 0) {
        float H[NE];
#pragma unroll
        for (int e = 0; e < NE; ++e) {
            float z  = an[e];
            float sp = (z > 0.f) ? (z + log1pf(expf(-z))) : log1pf(expf(z));
            H[e] = ag[e] + noise[e] * sp;
        }
        int e0 = 0; float v0 = H[0];
#pragma unroll
        for (int e = 1; e < NE; ++e) if (H[e] > v0) { v0 = H[e]; e0 = e; }
        int e1 = -1; float v1 = 0.f;
#pragma unroll
        for (int e = 0; e < NE; ++e)
            if (e != e0 && (e1 < 0 || H[e] > v1)) { v1 = H[e]; e1 = e; }
        float r  = expf(v1 - v0);
        float w0 = 1.f / (1.f + r), w1 = 1.f - w0;
        int p0 = atomicAdd(&cnt[e0], 1);
        idxl[(size_t)e0 * NR + p0] = row;  wl[(size_t)e0 * NR + p0] = w0;
        int p1 = atomicAdd(&cnt[NE + e1], 1);
        idxl[(size_t)(NE + e1) * NR + p1] = row;  wl[(size_t)(NE + e1) * NR + p1] = w1;
    }
}

// ---------------- grouped expert GEMM, all buckets in one dispatch -----------
// A[r][k] (gathered x rows), B[c][k] (= WeT), both staged by global_load_lds
// with XOR chunk swizzle applied on the SOURCE address (LDS linear dest).
__global__ __launch_bounds__(256, 2)
void moe_gemm(const ushort* __restrict__ xbf, const ushort* __restrict__ WeT,
              const float* __restrict__ be, const int* __restrict__ cnt,
              const int* __restrict__ idxl, const float* __restrict__ wl,
              float* __restrict__ out, float* __restrict__ y1,
              int bucket0, int use_y1) {
    __shared__ ushort Al[2][BM][GBK];     // 32 KB
    __shared__ ushort Bl[2][BM][GBK];     // 32 KB

    // bijective XCD swizzle (grid % 8 == 0): XCD gets a contiguous work chunk
    const int q8 = gridDim.x >> 3;
    const int W  = (blockIdx.x & 7) * q8 + (blockIdx.x >> 3);
    const int bucket = bucket0 + (W >> 8);      // 256 blocks per bucket
    const int t  = (W >> 3) & 31;
    const int cT = W & 7;
    const int count = cnt[bucket];
    if (t * BM >= count) return;
    const int nrowsv = min(BM, count - t * BM);
    const int e  = bucket & 7;
    const int c0 = cT * BN;
    const int*   rows = idxl + (size_t)bucket * NR + t * BM;
    const float* wrow = wl   + (size_t)bucket * NR + t * BM;

    const int tid = threadIdx.x, wid = tid >> 6, lane = tid & 63;
    const int wr = (wid >> 1) * 64, wc = (wid & 1) * 64;
    const int l16 = lane & 15, lhi = lane >> 4;
    const int lr8 = lane >> 3, lc8 = lane & 7;
    const int chunkp = lc8 ^ lr8;               // source chunk for swizzled LDS

    const ushort* aptr[4];
    const ushort* bptr[4];
#pragma unroll
    for (int q = 0; q < 4; ++q) {
        int r  = wid * 32 + q * 8 + lr8;
        int gr = rows[min(r, nrowsv - 1)];
        aptr[q] = xbf + (size_t)gr * DIM + chunkp * 8;
        int c = c0 + wid * 32 + q * 8 + lr8;
        bptr[q] = WeT + ((size_t)(e * DIM + c)) * DIM + chunkp * 8;
    }

    f32x4 acc[4][4];
#pragma unroll
    for (int m = 0; m < 4; ++m)
#pragma unroll
        for (int n = 0; n < 4; ++n) { f32x4 z = {0.f, 0.f, 0.f, 0.f}; acc[m][n] = z; }

    // prologue: stage tile 0 into buf 0
#pragma unroll
    for (int q = 0; q < 4; ++q) {
        gload16(aptr[q], &Al[0][wid * 32 + q * 8][0]);
        gload16(bptr[q], &Bl[0][wid * 32 + q * 8][0]);
    }

    for (int s = 0; s < DIM / GBK; ++s) {
        const int buf = s & 1;
        if (s + 1 < DIM / GBK) {
            const int nb = buf ^ 1, k0 = (s + 1) * GBK;
#pragma unroll
            for (int q = 0; q < 4; ++q) {
                gload16(aptr[q] + k0, &Al[nb][wid * 32 + q * 8][0]);
                gload16(bptr[q] + k0, &Bl[nb][wid * 32 + q * 8][0]);
            }
            asm volatile("s_waitcnt vmcnt(8)" ::: "memory");   // current tile landed
        } else {
            asm volatile("s_waitcnt vmcnt(0)" ::: "memory");
        }
        __builtin_amdgcn_s_barrier();

        const ushort* Ab = &Al[buf][0][0];
        const ushort* Bb = &Bl[buf][0][0];
#pragma unroll
        for (int h = 0; h < 2; ++h) {
            bf16x8 af[4], bfr[4];
            const int chb = (h * 4 + lhi) ^ (l16 & 7);
#pragma unroll
            for (int m = 0; m < 4; ++m) {
                int r = wr + m * 16 + l16;
                af[m] = *(const bf16x8*)(Ab + r * GBK + chb * 8);
            }
#pragma unroll
            for (int n = 0; n < 4; ++n) {
                int r = wc + n * 16 + l16;
                bfr[n] = *(const bf16x8*)(Bb + r * GBK + chb * 8);
            }
#pragma unroll
            for (int m = 0; m < 4; ++m)
#pragma unroll
                for (int n = 0; n < 4; ++n)
                    acc[m][n] = __builtin_amdgcn_mfma_f32_16x16x32_bf16(af[m], bfr[n], acc[m][n], 0, 0, 0);
        }
        asm volatile("s_waitcnt lgkmcnt(0)" ::: "memory");     // reads retired
        __builtin_amdgcn_s_barrier();                          // before next overwrite
    }

    float* dst = (bucket >= NE && use_y1) ? y1 : out;
    const bool accum = (bucket >= NE) && !use_y1;
    float bev[4];
#pragma unroll
    for (int n = 0; n < 4; ++n) bev[n] = be[(size_t)e * DIM + c0 + wc + n * 16 + l16];
#pragma unroll
    for (int m = 0; m < 4; ++m) {
#pragma unroll
        for (int r = 0; r < 4; ++r) {
            int rl = wr + m * 16 + lhi * 4 + r;
            if (rl < nrowsv) {
                int   gr = rows[rl];
                float w  = wrow[rl];
                float* op = dst + (size_t)gr * DIM + c0 + wc;
#pragma unroll
                for (int n = 0; n < 4; ++n) {
                    float v   = w * (acc[m][n][r] + bev[n]);
                    int   col = n * 16 + l16;
                    if (accum) op[col] += v; else op[col] = v;
                }
            }
        }
    }
}

// ---------------- out += Y1 --------------------------------------------------
__global__ __launch_bounds__(256)
void add_out(float* __restrict__ out, const float* __restrict__ y1) {
    const int n4 = NR * DIM / 4;
    for (int i = blockIdx.x * blockDim.x + threadIdx.x; i < n4; i += gridDim.x * blockDim.x) {
        float4 a = ((float4*)out)[i];
        float4 b = ((const float4*)y1)[i];
        a.x += b.x; a.y += b.y; a.z += b.z; a.w += b.w;
        ((float4*)out)[i] = a;
    }
}

extern "C" void kernel_launch(void* const* d_in, const int* in_sizes, int n_in,
                              void* d_out, int out_size, void* d_ws, size_t ws_size,
                              hipStream_t stream) {
    const float* x     = (const float*)d_in[0];
    const float* noise = (const float*)d_in[1];
    const float* Wg    = (const float*)d_in[2];
    const float* Wn    = (const float*)d_in[3];
    const float* We    = (const float*)d_in[4];
    const float* be    = (const float*)d_in[5];
    float* out = (float*)d_out;

    char* w = (char*)d_ws;
    size_t off = 256;
    int*   cnt  = (int*)w;
    int*   idxl = (int*)(w + off);  off += (size_t)2 * NE * NR * 4;   // 256 KB
    float* wl   = (float*)(w + off); off += (size_t)2 * NE * NR * 4;  // 256 KB
    off = (off + 255) & ~(size_t)255;
    ushort* xbf = (ushort*)(w + off); off += (size_t)NR * DIM * 2;        // 8 MB
    ushort* WeT = (ushort*)(w + off); off += (size_t)NE * DIM * DIM * 2;  // 16 MB
    float*  y1  = (float*)(w + off);
    size_t need_y1 = off + (size_t)NR * DIM * 4;                          // +16 MB
    const int use_y1 = (ws_size >= need_y1) ? 1 : 0;

    convert_x<<<1024, 256, 0, stream>>>(x, xbf, cnt);
    conv_we<<<NE * 16 * 16, 256, 0, stream>>>(We, WeT);
    gate_v2<<<NR / 16, 256, 0, stream>>>(x, noise, Wg, Wn, cnt, idxl, wl);

    if (use_y1) {
        moe_gemm<<<16 * 32 * 8, 256, 0, stream>>>(xbf, WeT, be, cnt, idxl, wl, out, y1, 0, 1);
        add_out<<<2048, 256, 0, stream>>>(out, y1);
    } else {
        moe_gemm<<<8 * 32 * 8, 256, 0, stream>>>(xbf, WeT, be, cnt, idxl, wl, out, nullptr, 0, 0);
        moe_gemm<<<8 * 32 * 8, 256, 0, stream>>>(xbf, WeT, be, cnt, idxl, wl, out, nullptr, 8, 0);
    }
}

// Round 3
// 123.123 us; speedup vs baseline: 3.4964x; 1.2337x over previous
//
#include <hip/hip_runtime.h>
#include <hip/hip_bf16.h>
#include <stdint.h>

#define NR   4096
#define DIM  1024
#define NE   8
#define BM   128
#define BN   128
#define GBK  64

typedef __attribute__((ext_vector_type(8))) short  bf16x8;
typedef __attribute__((ext_vector_type(8))) ushort u16x8;
typedef __attribute__((ext_vector_type(4))) float  f32x4;

__device__ __forceinline__ ushort f2bf(float f) {
    union { __hip_bfloat16 h; ushort u; } cv;
    cv.h = __float2bfloat16(f);   // RNE
    return cv.u;
}

__device__ __forceinline__ void gload16(const void* g, void* l) {
    __builtin_amdgcn_global_load_lds(
        (const __attribute__((address_space(1))) unsigned int*)g,
        (__attribute__((address_space(3))) unsigned int*)l, 16, 0, 0);
}

// ---------------- convert+transpose We: [e][k][c] f32 -> WeT [e][c][k] bf16 ---
// also zeroes the bucket counters (runs first on the stream)
__global__ __launch_bounds__(256)
void conv_we(const float* __restrict__ We, ushort* __restrict__ WeT, int* __restrict__ cnt) {
    if (blockIdx.x == 0 && threadIdx.x < 2 * NE) cnt[threadIdx.x] = 0;
    const int b  = blockIdx.x;              // e*256 + kt*16 + ct
    const int e  = b >> 8, kt = (b >> 4) & 15, ct = b & 15;
    __shared__ float T[64][68];             // 64x64 tile, padded
    const float* src = We + ((size_t)e * DIM + (size_t)kt * 64) * DIM + ct * 64;
#pragma unroll
    for (int j = 0; j < 4; ++j) {
        int idx = threadIdx.x + j * 256;    // 1024 float4 units (64 rows x 16)
        int r = idx >> 4, c4 = idx & 15;
        float4 v = *(const float4*)(src + (size_t)r * DIM + c4 * 4);
        *(float4*)&T[r][c4 * 4] = v;
    }
    __syncthreads();
    ushort* dst = WeT + ((size_t)e * DIM + (size_t)ct * 64) * DIM + kt * 64;
#pragma unroll
    for (int j = 0; j < 2; ++j) {
        int u = threadIdx.x + j * 256;      // 512 units: c=u/8, chunk=u%8 (8 bf16)
        int c = u >> 3, ch = u & 7;
        ushort tmp[8];
#pragma unroll
        for (int q = 0; q < 8; ++q) tmp[q] = f2bf(T[ch * 8 + q][c]);
        *(u16x8*)(dst + (size_t)c * DIM + ch * 8) = *(u16x8*)tmp;
    }
}

// ---------------- gating v3: W broadcast from LDS, 16 rows/block -------------
// thread (r = tid>>4, s = tid&15): row = blk*16+r, k-slice = j*64 + s*4.
// Also emits the bf16 copy of x (each element touched exactly once).
__global__ __launch_bounds__(256)
void gate_v3(const float* __restrict__ x, const float* __restrict__ noise,
             const float* __restrict__ Wg, const float* __restrict__ Wn,
             ushort* __restrict__ xbf,
             int* __restrict__ cnt, int* __restrict__ idxl, float* __restrict__ wl) {
    __shared__ float WL[16][DIM];           // rows 0..7: Wg^T, 8..15: Wn^T (64 KB)
    const int tid = threadIdx.x;
#pragma unroll
    for (int i = 0; i < 8; ++i) {
        int t4 = i * 256 + tid;             // 2048 float4 units per matrix
        int k  = t4 >> 1, e4 = (t4 & 1) * 4;
        float4 g = *(const float4*)(Wg + (size_t)k * NE + e4);
        float4 n = *(const float4*)(Wn + (size_t)k * NE + e4);
        WL[e4 + 0][k] = g.x; WL[e4 + 1][k] = g.y;
        WL[e4 + 2][k] = g.z; WL[e4 + 3][k] = g.w;
        WL[8 + e4 + 0][k] = n.x; WL[8 + e4 + 1][k] = n.y;
        WL[8 + e4 + 2][k] = n.z; WL[8 + e4 + 3][k] = n.w;
    }
    __syncthreads();

    const int s = tid & 15, r = tid >> 4;
    const int row = blockIdx.x * 16 + r;
    const float* xr = x + (size_t)row * DIM;
    ushort*     xbr = xbf + (size_t)row * DIM;

    float accg[NE], accn[NE];
#pragma unroll
    for (int e = 0; e < NE; ++e) { accg[e] = 0.f; accn[e] = 0.f; }

#pragma unroll
    for (int j = 0; j < 16; ++j) {
        const int k0 = j * 64 + s * 4;
        float4 xv = *(const float4*)(xr + k0);
        ushort4 xb;
        xb.x = f2bf(xv.x); xb.y = f2bf(xv.y); xb.z = f2bf(xv.z); xb.w = f2bf(xv.w);
        *(ushort4*)(xbr + k0) = xb;
#pragma unroll
        for (int e = 0; e < NE; ++e) {
            float4 wg = *(const float4*)&WL[e][k0];
            accg[e] += xv.x * wg.x + xv.y * wg.y + xv.z * wg.z + xv.w * wg.w;
        }
#pragma unroll
        for (int e = 0; e < NE; ++e) {
            float4 wn = *(const float4*)&WL[8 + e][k0];
            accn[e] += xv.x * wn.x + xv.y * wn.y + xv.z * wn.z + xv.w * wn.w;
        }
    }
#pragma unroll
    for (int e = 0; e < NE; ++e) {
#pragma unroll
        for (int off = 8; off; off >>= 1) {
            accg[e] += __shfl_down(accg[e], off, 16);
            accn[e] += __shfl_down(accn[e], off, 16);
        }
    }
    if (s == 0) {
        float H[NE];
#pragma unroll
        for (int e = 0; e < NE; ++e) {
            float z  = accn[e];
            float sp = (z > 0.f) ? (z + log1pf(expf(-z))) : log1pf(expf(z));
            H[e] = accg[e] + noise[e] * sp;
        }
        int e0 = 0; float v0 = H[0];
#pragma unroll
        for (int e = 1; e < NE; ++e) if (H[e] > v0) { v0 = H[e]; e0 = e; }
        int e1 = -1; float v1 = 0.f;
#pragma unroll
        for (int e = 0; e < NE; ++e)
            if (e != e0 && (e1 < 0 || H[e] > v1)) { v1 = H[e]; e1 = e; }
        float rr = expf(v1 - v0);
        float w0 = 1.f / (1.f + rr), w1 = 1.f - w0;
        int p0 = atomicAdd(&cnt[e0], 1);
        idxl[(size_t)e0 * NR + p0] = row;  wl[(size_t)e0 * NR + p0] = w0;
        int p1 = atomicAdd(&cnt[NE + e1], 1);
        idxl[(size_t)(NE + e1) * NR + p1] = row;  wl[(size_t)(NE + e1) * NR + p1] = w1;
    }
}

// ---------------- grouped expert GEMM, all buckets in one dispatch -----------
__global__ __launch_bounds__(256, 2)
void moe_gemm(const ushort* __restrict__ xbf, const ushort* __restrict__ WeT,
              const float* __restrict__ be, const int* __restrict__ cnt,
              const int* __restrict__ idxl, const float* __restrict__ wl,
              float* __restrict__ out, float* __restrict__ y1,
              int bucket0, int use_y1) {
    __shared__ ushort Al[2][BM][GBK];     // 32 KB
    __shared__ ushort Bl[2][BM][GBK];     // 32 KB

    const int q8 = gridDim.x >> 3;
    const int W  = (blockIdx.x & 7) * q8 + (blockIdx.x >> 3);
    const int bucket = bucket0 + (W >> 8);
    const int t  = (W >> 3) & 31;
    const int cT = W & 7;
    const int count = cnt[bucket];
    if (t * BM >= count) return;
    const int nrowsv = min(BM, count - t * BM);
    const int e  = bucket & 7;
    const int c0 = cT * BN;
    const int*   rows = idxl + (size_t)bucket * NR + t * BM;
    const float* wrow = wl   + (size_t)bucket * NR + t * BM;

    const int tid = threadIdx.x, wid = tid >> 6, lane = tid & 63;
    const int wr = (wid >> 1) * 64, wc = (wid & 1) * 64;
    const int l16 = lane & 15, lhi = lane >> 4;
    const int lr8 = lane >> 3, lc8 = lane & 7;
    const int chunkp = lc8 ^ lr8;

    const ushort* aptr[4];
    const ushort* bptr[4];
#pragma unroll
    for (int q = 0; q < 4; ++q) {
        int r  = wid * 32 + q * 8 + lr8;
        int gr = rows[min(r, nrowsv - 1)];
        aptr[q] = xbf + (size_t)gr * DIM + chunkp * 8;
        int c = c0 + wid * 32 + q * 8 + lr8;
        bptr[q] = WeT + ((size_t)(e * DIM + c)) * DIM + chunkp * 8;
    }

    f32x4 acc[4][4];
#pragma unroll
    for (int m = 0; m < 4; ++m)
#pragma unroll
        for (int n = 0; n < 4; ++n) { f32x4 z = {0.f, 0.f, 0.f, 0.f}; acc[m][n] = z; }

#pragma unroll
    for (int q = 0; q < 4; ++q) {
        gload16(aptr[q], &Al[0][wid * 32 + q * 8][0]);
        gload16(bptr[q], &Bl[0][wid * 32 + q * 8][0]);
    }

    for (int s = 0; s < DIM / GBK; ++s) {
        const int buf = s & 1;
        if (s + 1 < DIM / GBK) {
            const int nb = buf ^ 1, k0 = (s + 1) * GBK;
#pragma unroll
            for (int q = 0; q < 4; ++q) {
                gload16(aptr[q] + k0, &Al[nb][wid * 32 + q * 8][0]);
                gload16(bptr[q] + k0, &Bl[nb][wid * 32 + q * 8][0]);
            }
            asm volatile("s_waitcnt vmcnt(8)" ::: "memory");
        } else {
            asm volatile("s_waitcnt vmcnt(0)" ::: "memory");
        }
        __builtin_amdgcn_s_barrier();

        const ushort* Ab = &Al[buf][0][0];
        const ushort* Bb = &Bl[buf][0][0];
#pragma unroll
        for (int h = 0; h < 2; ++h) {
            bf16x8 af[4], bfr[4];
            const int chb = (h * 4 + lhi) ^ (l16 & 7);
#pragma unroll
            for (int m = 0; m < 4; ++m) {
                int rr = wr + m * 16 + l16;
                af[m] = *(const bf16x8*)(Ab + rr * GBK + chb * 8);
            }
#pragma unroll
            for (int n = 0; n < 4; ++n) {
                int rr = wc + n * 16 + l16;
                bfr[n] = *(const bf16x8*)(Bb + rr * GBK + chb * 8);
            }
#pragma unroll
            for (int m = 0; m < 4; ++m)
#pragma unroll
                for (int n = 0; n < 4; ++n)
                    acc[m][n] = __builtin_amdgcn_mfma_f32_16x16x32_bf16(af[m], bfr[n], acc[m][n], 0, 0, 0);
        }
        asm volatile("s_waitcnt lgkmcnt(0)" ::: "memory");
        __builtin_amdgcn_s_barrier();
    }

    float* dst = (bucket >= NE && use_y1) ? y1 : out;
    const bool accum = (bucket >= NE) && !use_y1;
    float bev[4];
#pragma unroll
    for (int n = 0; n < 4; ++n) bev[n] = be[(size_t)e * DIM + c0 + wc + n * 16 + l16];
#pragma unroll
    for (int m = 0; m < 4; ++m) {
#pragma unroll
        for (int r = 0; r < 4; ++r) {
            int rl = wr + m * 16 + lhi * 4 + r;
            if (rl < nrowsv) {
                int   gr = rows[rl];
                float w  = wrow[rl];
                float* op = dst + (size_t)gr * DIM + c0 + wc;
#pragma unroll
                for (int n = 0; n < 4; ++n) {
                    float v   = w * (acc[m][n][r] + bev[n]);
                    int   col = n * 16 + l16;
                    if (accum) op[col] += v; else op[col] = v;
                }
            }
        }
    }
}

// ---------------- out += Y1 --------------------------------------------------
__global__ __launch_bounds__(256)
void add_out(float* __restrict__ out, const float* __restrict__ y1) {
    const int n4 = NR * DIM / 4;
    for (int i = blockIdx.x * blockDim.x + threadIdx.x; i < n4; i += gridDim.x * blockDim.x) {
        float4 a = ((float4*)out)[i];
        float4 b = ((const float4*)y1)[i];
        a.x += b.x; a.y += b.y; a.z += b.z; a.w += b.w;
        ((float4*)out)[i] = a;
    }
}

extern "C" void kernel_launch(void* const* d_in, const int* in_sizes, int n_in,
                              void* d_out, int out_size, void* d_ws, size_t ws_size,
                              hipStream_t stream) {
    const float* x     = (const float*)d_in[0];
    const float* noise = (const float*)d_in[1];
    const float* Wg    = (const float*)d_in[2];
    const float* Wn    = (const float*)d_in[3];
    const float* We    = (const float*)d_in[4];
    const float* be    = (const float*)d_in[5];
    float* out = (float*)d_out;

    char* w = (char*)d_ws;
    size_t off = 256;
    int*   cnt  = (int*)w;
    int*   idxl = (int*)(w + off);  off += (size_t)2 * NE * NR * 4;
    float* wl   = (float*)(w + off); off += (size_t)2 * NE * NR * 4;
    off = (off + 255) & ~(size_t)255;
    ushort* xbf = (ushort*)(w + off); off += (size_t)NR * DIM * 2;        // 8 MB
    ushort* WeT = (ushort*)(w + off); off += (size_t)NE * DIM * DIM * 2;  // 16 MB
    float*  y1  = (float*)(w + off);
    size_t need_y1 = off + (size_t)NR * DIM * 4;                          // +16 MB
    const int use_y1 = (ws_size >= need_y1) ? 1 : 0;

    conv_we<<<NE * 16 * 16, 256, 0, stream>>>(We, WeT, cnt);
    gate_v3<<<NR / 16, 256, 0, stream>>>(x, noise, Wg, Wn, xbf, cnt, idxl, wl);

    if (use_y1) {
        moe_gemm<<<16 * 32 * 8, 256, 0, stream>>>(xbf, WeT, be, cnt, idxl, wl, out, y1, 0, 1);
        add_out<<<2048, 256, 0, stream>>>(out, y1);
    } else {
        moe_gemm<<<8 * 32 * 8, 256, 0, stream>>>(xbf, WeT, be, cnt, idxl, wl, out, nullptr, 0, 0);
        moe_gemm<<<8 * 32 * 8, 256, 0, stream>>>(xbf, WeT, be, cnt, idxl, wl, out, nullptr, 8, 0);
    }
}